// Round 3
// baseline (36.427 us; speedup 1.0000x reference)
//
#include <hip/hip_runtime.h>

// Y[b,e,k,j] = sum_i X[b, ind[b,e,k], i] * W[e,i,j]
// X:[B,T,I] f32, ind:[B,E,K] int32, W:[E,I,J] f32 -> Y:[B,E,K,J] f32
#define B_ 8
#define T_ 8192
#define I_ 128
#define E_ 16
#define J_ 128
#define K_ 1024
#define ROWS 128   // k-rows per block

typedef unsigned short u16;
typedef unsigned int   u32;
typedef __attribute__((ext_vector_type(8))) short s8v;   // 8 bf16 = 4 VGPRs
typedef __attribute__((ext_vector_type(4))) float f4v;   // MFMA accumulator

__device__ __forceinline__ u16 f2bf(float f) {
    union { float f; u32 u; } v; v.f = f;
    const u32 u = v.u;
    return (u16)((u + 0x7fffu + ((u >> 16) & 1u)) >> 16);  // RNE
}

// ---- Prepass: Wt[e][j][i] = bf16(W[e][i][j]) ----
__global__ void convert_wt(const float* __restrict__ W, u16* __restrict__ Wt) {
    const int t  = blockIdx.x * 256 + threadIdx.x;  // 32768 threads
    const int o8 = t * 8;                           // 8 outputs along i
    const int e  = o8 >> 14;
    const int r  = o8 & 16383;
    const int j  = r >> 7;
    const int i0 = r & 127;
    const float* Wp = W + e * (I_ * J_) + j;        // column j of W[e]
    s8v o;
#pragma unroll
    for (int u = 0; u < 8; ++u)
        o[u] = (short)f2bf(Wp[(i0 + u) * J_]);
    *reinterpret_cast<s8v*>(Wt + o8) = o;
}

// ---- Main: gather + bf16 MFMA GEMM ----
// 512 threads (8 waves), ROWS=128. LDS (XOR-swizzled byte^=((row&7)<<4)):
//   WsT[j][i] 128x128 bf16 = 32KB, Xs[r][i] 128x128 bf16 = 32KB -> 64KB,
//   2 blocks/CU = 16 waves/CU.
template<bool PRE>
__global__ __launch_bounds__(512, 4)
void gather_mfma(const float* __restrict__ X, const int* __restrict__ ind,
                 const void* __restrict__ Wsrc, float* __restrict__ Y) {
    __shared__ u16 WsT[I_ * J_];
    __shared__ u16 Xs[ROWS * I_];

    const int t    = threadIdx.x;
    const int wave = t >> 6;
    const int lane = t & 63;

    // XCD swizzle: grid=1024, 8 XCDs -> XCD x owns bid x*128..x*128+127,
    // i.e. exactly batch b = x (X[b] 4MB L2-resident per XCD).
    const int orig = blockIdx.x;
    const int bid  = (orig & 7) * 128 + (orig >> 3);
    const int kt = bid & 7;              // K_/ROWS = 8
    const int be = bid >> 3;
    const int e  = be & (E_ - 1);
    const int b  = be >> 4;
    const int k0 = kt * ROWS;

    // ---- Stage WsT ----
    if (PRE) {
        const s8v* Wg = reinterpret_cast<const s8v*>((const u16*)Wsrc + (size_t)e * (I_ * J_));
#pragma unroll
        for (int u = 0; u < 4; ++u) {
            const int c   = t + 512 * u;          // 16B chunk id, 0..2047
            const int row = c >> 4;               // j
            const s8v v = Wg[c];
            *reinterpret_cast<s8v*>((char*)WsT + ((c * 16) ^ ((row & 7) << 4))) = v;
        }
    } else {
        const float* We = (const float*)Wsrc + (size_t)e * (I_ * J_);
#pragma unroll
        for (int u = 0; u < 8; ++u) {
            const int f4i = t + 512 * u;          // float4 id, 0..4095
            const int i   = f4i >> 5;
            const int j0  = (f4i & 31) * 4;
            const float4 w4 = reinterpret_cast<const float4*>(We)[f4i];
            const float ws[4] = {w4.x, w4.y, w4.z, w4.w};
#pragma unroll
            for (int q = 0; q < 4; ++q) {
                const int j = j0 + q;
                *(u16*)((char*)WsT + ((j * 256 + i * 2) ^ ((j & 7) << 4))) = f2bf(ws[q]);
            }
        }
    }

    // ---- Stage Xs: gather 128 rows, convert f32->bf16 ----
    {
        const int r   = t >> 2;                   // row 0..127
        const int q   = t & 3;                    // 32-elem quarter
        const int idx = ind[(size_t)be * K_ + k0 + r];
        const float4* Xr = reinterpret_cast<const float4*>(X + ((size_t)b * T_ + idx) * I_) + q * 8;
        const int sx = (r & 7) << 4;
        char* xrow = (char*)Xs + r * 256;
#pragma unroll
        for (int u = 0; u < 4; ++u) {
            const float4 a = Xr[2 * u], c = Xr[2 * u + 1];
            s8v o;
            o[0] = (short)f2bf(a.x); o[1] = (short)f2bf(a.y);
            o[2] = (short)f2bf(a.z); o[3] = (short)f2bf(a.w);
            o[4] = (short)f2bf(c.x); o[5] = (short)f2bf(c.y);
            o[6] = (short)f2bf(c.z); o[7] = (short)f2bf(c.w);
            *reinterpret_cast<s8v*>(xrow + ((q * 64 + u * 16) ^ sx)) = o;
        }
    }
    __syncthreads();

    // ---- Compute: wave = (k-quarter rq, j-half jh); 32 k-rows x 64 j-cols ----
    // Swapped operands: A = W^T tile (m=j), B = X^T tile (n=k-row).
    // Same k-map for A and B (verified round 1) -> exact pairing.
    const int rq  = wave >> 1;          // 0..3
    const int jh  = wave & 1;
    const int g   = lane >> 4;
    const int l15 = lane & 15;
    const int sx  = (lane & 7) << 4;

    f4v acc[2][4];
#pragma unroll
    for (int tr = 0; tr < 2; ++tr)
#pragma unroll
        for (int nj = 0; nj < 4; ++nj)
#pragma unroll
            for (int r = 0; r < 4; ++r) acc[tr][nj][r] = 0.f;

    const char* xb = (const char*)Xs  + (size_t)(rq * 32 + l15) * 256;
    const char* wb = (const char*)WsT + (size_t)(jh * 64 + l15) * 256;
#pragma unroll
    for (int s = 0; s < 4; ++s) {
        const int off = (s * 64 + g * 16) ^ sx;
        const s8v x0 = *reinterpret_cast<const s8v*>(xb + off);
        const s8v x1 = *reinterpret_cast<const s8v*>(xb + 16 * 256 + off);
#pragma unroll
        for (int nj = 0; nj < 4; ++nj) {
            const s8v wf = *reinterpret_cast<const s8v*>(wb + nj * 16 * 256 + off);
            acc[0][nj] = __builtin_amdgcn_mfma_f32_16x16x32_bf16(wf, x0, acc[0][nj], 0, 0, 0);
            acc[1][nj] = __builtin_amdgcn_mfma_f32_16x16x32_bf16(wf, x1, acc[1][nj], 0, 0, 0);
        }
    }

    // ---- Store: D col = k-row (lane&15), row = j (4g+reg) -> float4 per acc,
    //      nontemporal (Y is write-once; keep X resident in L2) ----
    float* Yb = Y + ((size_t)be * K_ + k0) * J_;
    const int kbase = rq * 32 + l15;
#pragma unroll
    for (int tr = 0; tr < 2; ++tr) {
        float* rowp = Yb + (size_t)(kbase + tr * 16) * J_ + jh * 64 + g * 4;
#pragma unroll
        for (int nj = 0; nj < 4; ++nj)
            __builtin_nontemporal_store(acc[tr][nj], reinterpret_cast<f4v*>(rowp + nj * 16));
    }
}

extern "C" void kernel_launch(void* const* d_in, const int* in_sizes, int n_in,
                              void* d_out, int out_size, void* d_ws, size_t ws_size,
                              hipStream_t stream) {
    (void)in_sizes; (void)n_in; (void)out_size;
    const float* X   = (const float*)d_in[0];
    const int*   ind = (const int*)d_in[1];
    const float* W   = (const float*)d_in[2];
    float*       Y   = (float*)d_out;

    const size_t wt_bytes = (size_t)E_ * I_ * J_ * sizeof(u16);  // 512 KB
    const int grid = B_ * E_ * (K_ / ROWS);                       // 1024

    if (ws_size >= wt_bytes && d_ws != nullptr) {
        u16* Wt = (u16*)d_ws;
        hipLaunchKernelGGL(convert_wt, dim3(E_ * I_ * J_ / (256 * 8)), dim3(256), 0, stream, W, Wt);
        hipLaunchKernelGGL((gather_mfma<true>), dim3(grid), dim3(512), 0, stream,
                           X, ind, (const void*)Wt, Y);
    } else {
        hipLaunchKernelGGL((gather_mfma<false>), dim3(grid), dim3(512), 0, stream,
                           X, ind, (const void*)W, Y);
    }
}

// Round 4
// 35.579 us; speedup vs baseline: 1.0238x; 1.0238x over previous
//
#include <hip/hip_runtime.h>

// Y[b,e,k,j] = sum_i X[b, ind[b,e,k], i] * W[e,i,j]
// X:[B,T,I] f32, ind:[B,E,K] int32, W:[E,I,J] f32 -> Y:[B,E,K,J] f32
#define B_ 8
#define T_ 8192
#define I_ 128
#define E_ 16
#define J_ 128
#define K_ 1024
#define ROWS 64   // k-rows per block

typedef unsigned short u16;
typedef unsigned int   u32;
typedef __attribute__((ext_vector_type(8))) short s8v;   // 8 bf16 = 4 VGPRs
typedef __attribute__((ext_vector_type(4))) float f4v;   // MFMA accumulator

__device__ __forceinline__ u16 f2bf(float f) {
    union { float f; u32 u; } v; v.f = f;
    const u32 u = v.u;
    return (u16)((u + 0x7fffu + ((u >> 16) & 1u)) >> 16);  // RNE
}

__device__ __forceinline__ void gload_lds16(const void* g, void* l) {
    __builtin_amdgcn_global_load_lds(
        (const __attribute__((address_space(1))) u32*)g,
        (__attribute__((address_space(3))) u32*)l, 16, 0, 0);
}

// ---- Prepass: write PRE-SWIZZLED bf16 W^T image per expert ----
// img chunk c (16B, c=0..2047): j = c>>4, i0 = (c&15)*8, holds bf16 W[e][i0..i0+7][j]
// at image byte offset (c*16) ^ ((j&7)<<4)  == exact LDS image the main kernel wants.
__global__ void convert_wt(const float* __restrict__ W, u16* __restrict__ Wt) {
    __shared__ float Wf[I_ * 129];   // padded transpose buffer (64.5 KB)
    const int e = blockIdx.x;
    const int t = threadIdx.x;
    const float* We = W + (size_t)e * (I_ * J_);
#pragma unroll
    for (int u = 0; u < 16; ++u) {
        const int f4 = t + 256 * u;          // float4 id 0..4095 (coalesced)
        const int i  = f4 >> 5;
        const int c0 = (f4 & 31) * 4;
        const float4 v = reinterpret_cast<const float4*>(We)[f4];
        float* p = &Wf[i * 129 + c0];
        p[0] = v.x; p[1] = v.y; p[2] = v.z; p[3] = v.w;
    }
    __syncthreads();
    char* img = (char*)Wt + (size_t)e * (I_ * J_ * 2);
#pragma unroll
    for (int u2 = 0; u2 < 8; ++u2) {
        const int c  = t + 256 * u2;
        const int j  = c >> 4;
        const int i0 = (c & 15) * 8;
        s8v o;
#pragma unroll
        for (int u = 0; u < 8; ++u)
            o[u] = (short)f2bf(Wf[(i0 + u) * 129 + j]);
        *reinterpret_cast<s8v*>(img + ((c * 16) ^ ((j & 7) << 4))) = o;  // coalesced per 256B
    }
}

// ---- Main: gather + bf16 MFMA GEMM ----
// 256 threads, ROWS=64. LDS: WsT 32KB + Xs 16KB = 48KB -> 3 blocks/CU (12 waves/CU).
template<bool PRE>
__global__ __launch_bounds__(256, 3)
void gather_mfma(const float* __restrict__ X, const int* __restrict__ ind,
                 const void* __restrict__ Wsrc, float* __restrict__ Y) {
    __shared__ u16 WsT[I_ * J_];
    __shared__ u16 Xs[ROWS * I_];

    const int t    = threadIdx.x;
    const int wave = t >> 6;
    const int lane = t & 63;

    const int kt = blockIdx.x & 15;      // K_/ROWS = 16
    const int be = blockIdx.x >> 4;
    const int e  = be & (E_ - 1);
    const int b  = be >> 4;
    const int k0 = kt * ROWS;

    // ---- Stage WsT: async linear copy of the pre-swizzled image ----
    if (PRE) {
        const char* Wimg = (const char*)Wsrc + (size_t)e * 32768;
#pragma unroll
        for (int u = 0; u < 8; ++u) {
            const int off = (wave * 8 + u) * 1024;       // wave-uniform LDS dest
            gload_lds16(Wimg + off + lane * 16, (char*)WsT + off);
        }
    } else {
        // Fallback: transpose+convert W[e] (f32 [i][j]) inline.
        const float* We = (const float*)Wsrc + (size_t)e * (I_ * J_);
#pragma unroll
        for (int u = 0; u < 16; ++u) {
            const int f4i = t + 256 * u;          // float4 id, 0..4095
            const int i   = f4i >> 5;
            const int j0  = (f4i & 31) * 4;
            const float4 w4 = reinterpret_cast<const float4*>(We)[f4i];
            const float ws[4] = {w4.x, w4.y, w4.z, w4.w};
#pragma unroll
            for (int q = 0; q < 4; ++q) {
                const int j = j0 + q;
                *(u16*)((char*)WsT + ((j * 256 + i * 2) ^ ((j & 7) << 4))) = f2bf(ws[q]);
            }
        }
    }

    // ---- Stage Xs: gather 64 rows, convert f32->bf16, swizzled ds_write ----
    {
        const int r   = t >> 2;                   // row 0..63
        const int q   = t & 3;                    // 32-elem quarter
        const int idx = ind[(size_t)be * K_ + k0 + r];
        const float4* Xr = reinterpret_cast<const float4*>(X + ((size_t)b * T_ + idx) * I_) + q * 8;
        const int sxr = (r & 7) << 4;
        char* xrow = (char*)Xs + r * 256;
#pragma unroll
        for (int u = 0; u < 4; ++u) {
            const float4 a = Xr[2 * u], c = Xr[2 * u + 1];
            s8v o;
            o[0] = (short)f2bf(a.x); o[1] = (short)f2bf(a.y);
            o[2] = (short)f2bf(a.z); o[3] = (short)f2bf(a.w);
            o[4] = (short)f2bf(c.x); o[5] = (short)f2bf(c.y);
            o[6] = (short)f2bf(c.z); o[7] = (short)f2bf(c.w);
            *reinterpret_cast<s8v*>(xrow + ((q * 64 + u * 16) ^ sxr)) = o;
        }
    }
    __syncthreads();   // drains vmcnt -> W copy complete

    // ---- Compute: wave = (k-half rh, j-half jh); 32 k-rows x 64 j-cols ----
    // Swapped operands: A = W^T tile (m=j), B = X tile (n=k-row).
    // Identical k-map on A and B -> exact for any true per-lane K order.
    const int rh  = wave >> 1;
    const int jh  = wave & 1;
    const int g   = lane >> 4;
    const int l15 = lane & 15;
    const int sx  = (lane & 7) << 4;

    f4v acc[2][4];
#pragma unroll
    for (int tr = 0; tr < 2; ++tr)
#pragma unroll
        for (int nj = 0; nj < 4; ++nj)
#pragma unroll
            for (int r = 0; r < 4; ++r) acc[tr][nj][r] = 0.f;

    const char* xb = (const char*)Xs  + (size_t)(rh * 32 + l15) * 256;
    const char* wb = (const char*)WsT + (size_t)(jh * 64 + l15) * 256;
#pragma unroll
    for (int s = 0; s < 4; ++s) {
        const int off = (s * 64 + g * 16) ^ sx;
        const s8v x0 = *reinterpret_cast<const s8v*>(xb + off);
        const s8v x1 = *reinterpret_cast<const s8v*>(xb + 16 * 256 + off);
#pragma unroll
        for (int nj = 0; nj < 4; ++nj) {
            const s8v wf = *reinterpret_cast<const s8v*>(wb + nj * 16 * 256 + off);
            acc[0][nj] = __builtin_amdgcn_mfma_f32_16x16x32_bf16(wf, x0, acc[0][nj], 0, 0, 0);
            acc[1][nj] = __builtin_amdgcn_mfma_f32_16x16x32_bf16(wf, x1, acc[1][nj], 0, 0, 0);
        }
    }

    // ---- Store: thread (g,l15) holds Y[k = rh*32+tr*16+l15][j = jh*64+nj*16+4g+r]
    //      -> contiguous float4 along j, through L2 (write-coalesced) ----
    float* Yb = Y + ((size_t)be * K_ + k0) * J_;
#pragma unroll
    for (int tr = 0; tr < 2; ++tr) {
        float* rowp = Yb + (size_t)(rh * 32 + tr * 16 + l15) * J_ + jh * 64 + g * 4;
#pragma unroll
        for (int nj = 0; nj < 4; ++nj)
            *reinterpret_cast<f4v*>(rowp + nj * 16) = acc[tr][nj];
    }
}

extern "C" void kernel_launch(void* const* d_in, const int* in_sizes, int n_in,
                              void* d_out, int out_size, void* d_ws, size_t ws_size,
                              hipStream_t stream) {
    (void)in_sizes; (void)n_in; (void)out_size;
    const float* X   = (const float*)d_in[0];
    const int*   ind = (const int*)d_in[1];
    const float* W   = (const float*)d_in[2];
    float*       Y   = (float*)d_out;

    const size_t wt_bytes = (size_t)E_ * I_ * J_ * sizeof(u16);  // 512 KB
    const int grid = B_ * E_ * (K_ / ROWS);                       // 2048

    if (ws_size >= wt_bytes && d_ws != nullptr) {
        u16* Wt = (u16*)d_ws;
        hipLaunchKernelGGL(convert_wt, dim3(E_), dim3(256), 0, stream, W, Wt);
        hipLaunchKernelGGL((gather_mfma<true>), dim3(grid), dim3(256), 0, stream,
                           X, ind, (const void*)Wt, Y);
    } else {
        hipLaunchKernelGGL((gather_mfma<false>), dim3(grid), dim3(256), 0, stream,
                           X, ind, (const void*)W, Y);
    }
}